// Round 7
// baseline (1738.190 us; speedup 1.0000x reference)
//
#include <hip/hip_runtime.h>
#include <hip/hip_bf16.h>

#define NB   32
#define SEQ  512
#define HID  768
#define FFN  3072
#define NEXP 8

typedef float f32x4 __attribute__((ext_vector_type(4)));
typedef short s16x8 __attribute__((ext_vector_type(8)));

__device__ __forceinline__ unsigned short f2bf(float f) {
    return __builtin_bit_cast(unsigned short, (__bf16)f);
}

__device__ __forceinline__ float fast_exp2(float x) {
    float r; asm("v_exp_f32 %0, %1" : "=v"(r) : "v"(x)); return r;
}
__device__ __forceinline__ float fast_rcp(float x) {
    float r; asm("v_rcp_f32 %0, %1" : "=v"(r) : "v"(x)); return r;
}

// tanh-gelu, overflow-free (exp2 arg <= 0). |error| vs exact-erf gelu ~2e-4.
__device__ __forceinline__ float gelu_fast(float v) {
    float u  = v * (0.7978845608f + 0.0356774081f * v * v);
    float t  = fast_exp2(-2.8853900817779268f * fabsf(u));   // e^{-2|u|}
    float T  = (1.0f - t) * fast_rcp(1.0f + t);              // tanh(|u|)
    return 0.5f * v + 0.5f * fabsf(v) * T;
}

#define GLOAD16(gp, lp) __builtin_amdgcn_global_load_lds( \
    (const __attribute__((address_space(1))) unsigned int*)(gp), \
    (__attribute__((address_space(3))) unsigned int*)(lp), 16, 0, 0)

// ---------------------------------------------------------------------------
// stable counting-sort permutation of sentences by expert label (1 wave)
// ---------------------------------------------------------------------------
__global__ void sort_labels_kernel(const int* __restrict__ labels, int* __restrict__ perm)
{
    int i = threadIdx.x;
    if (i < NB) {
        int li = labels[i];
        int rank = 0;
        for (int j = 0; j < NB; j++) {
            int lj = labels[j];
            if (lj < li || (lj == li && j < i)) rank++;
        }
        perm[rank] = i;
    }
}

// ---------------------------------------------------------------------------
// convert X fp32 -> bf16
// ---------------------------------------------------------------------------
__global__ __launch_bounds__(256) void cvt_x_kernel(
    const float* __restrict__ X, unsigned short* __restrict__ Xb, int n8)
{
    int idx = blockIdx.x * blockDim.x + threadIdx.x;
    int stride = gridDim.x * blockDim.x;
    for (int i = idx; i < n8; i += stride) {
        f32x4 a = *(const f32x4*)(X + (size_t)i * 8);
        f32x4 b = *(const f32x4*)(X + (size_t)i * 8 + 4);
        unsigned short o[8];
#pragma unroll
        for (int v = 0; v < 4; v++) o[v] = f2bf(a[v]);
#pragma unroll
        for (int v = 0; v < 4; v++) o[4 + v] = f2bf(b[v]);
        *(s16x8*)(Xb + (size_t)i * 8) = *(s16x8*)o;
    }
}

// ---------------------------------------------------------------------------
// convert + transpose: in [R][C] fp32 -> out [C][R] bf16 per slab
// ---------------------------------------------------------------------------
__global__ __launch_bounds__(256) void cvt_transpose_kernel(
    const float* __restrict__ W, unsigned short* __restrict__ WT, int R, int C)
{
    __shared__ unsigned short tile[64][65];
    const int cb = blockIdx.x * 64, rb = blockIdx.y * 64;
    const float* src = W + (size_t)blockIdx.z * R * C;
    unsigned short* dst = WT + (size_t)blockIdx.z * R * C;
    const int x = threadIdx.x & 63, y0 = threadIdx.x >> 6;
#pragma unroll
    for (int i = 0; i < 16; i++) {
        int r = y0 + i * 4;
        tile[r][x] = f2bf(src[(size_t)(rb + r) * C + cb + x]);
    }
    __syncthreads();
#pragma unroll
    for (int i = 0; i < 16; i++) {
        int c = y0 + i * 4;
        dst[(size_t)(cb + c) * R + rb + x] = tile[x][c];
    }
}

// ---------------------------------------------------------------------------
// 256x256 8-phase RING GEMM (BK=64, 8 waves, ONE 64 KB LDS buffer -> 2 blk/CU)
// A = smem[0..32K) [256 rows x 128 B], B = smem[32K..64K).
// Regions (16 KB): A-half h rows {h*64..}U{128+h*64..}; B-half h rows
// {h*32..}U{64+h*32..}U{128+h*32..}U{192+h*32..}. Swizzle: both-sides XOR.
//
// Window t (frag-persistent; regions re-staged 1 phase after last read,
// landing 3 phases before next read). Per-wave issue: wp1:4, wp2:2, wp3:2.
//   wp0 (A0,B0): read a<-A0(8), b0<-B0(4);           guard vmcnt(2)->bar
//   wp1 (A0,B1): read b1<-B1(4); stage A0,B0(t+1);   guard vmcnt(4)->bar
//   wp2 (A1,B1): read a<-A1(8);  stage B1(t+1);      bar
//   wp3 (A1,B0): regs only;      stage A1(t+1);      guard vmcnt(4)->bar
// Guards verified per-wave: wp0-guard waits B1(t) (oldest 2 of 4), wp1-guard
// waits A1(t) (oldest 2 of 6), wp3-guard waits A0B0(t+1) (oldest 4 of 8).
// Last window: no stages; guards (2, 0, none).
// ---------------------------------------------------------------------------
template<int LDB, bool ISA>
__device__ __forceinline__ void stage_region(const char* g, char* lds, int half, int tid)
{
#pragma unroll
    for (int p = 0; p < 2; p++) {
        int L  = p * 8192 + tid * 16;
        int rr = L >> 7;
        int cb = L & 127;
        int row = ISA ? ((rr & 63) + ((rr >> 6) << 7) + half * 64)
                      : ((rr & 31) + ((rr >> 5) << 6) + half * 32);
        int cbs = cb ^ ((row & 7) << 4);
        GLOAD16(g + (size_t)row * LDB + cbs, lds + (size_t)row * 128 + cb);
    }
}

__device__ __forceinline__ void read_af(const char* Ab, int arow_b, int k0, int ih, s16x8 (&a)[2][4])
{
    const int k1 = k0 ^ 64;
#pragma unroll
    for (int i = 0; i < 4; i++) {
        const char* p = Ab + arow_b + (ih * 64 + i * 16) * 128;
        a[0][i] = *(const s16x8*)(p + k0);
        a[1][i] = *(const s16x8*)(p + k1);
    }
}
__device__ __forceinline__ void read_bf(const char* Bb, int brow_b, int k0, int jh, s16x8 (&b)[2][2])
{
    const int k1 = k0 ^ 64;
#pragma unroll
    for (int j = 0; j < 2; j++) {
        const char* p = Bb + brow_b + (jh * 32 + j * 16) * 128;
        b[0][j] = *(const s16x8*)(p + k0);
        b[1][j] = *(const s16x8*)(p + k1);
    }
}

template<int IH, int JH>
__device__ __forceinline__ void mfma_quad(s16x8 (&a)[2][4], s16x8 (&b)[2][2], f32x4 (&acc)[8][4])
{
    __builtin_amdgcn_s_setprio(1);
#pragma unroll
    for (int kk = 0; kk < 2; kk++)
#pragma unroll
        for (int i = 0; i < 4; i++)
#pragma unroll
            for (int j = 0; j < 2; j++)
                acc[IH * 4 + i][JH * 2 + j] = __builtin_amdgcn_mfma_f32_16x16x32_bf16(
                    a[kk][i], b[kk][j], acc[IH * 4 + i][JH * 2 + j], 0, 0, 0);
    __builtin_amdgcn_s_setprio(0);
}

#define VMCNT(N) asm volatile("s_waitcnt vmcnt(%0)" :: "i"(N) : "memory")

template<int LDB, bool STG, int W0, int W1V, int WEND>
__device__ __forceinline__ void gwindow(const char* AgN, const char* BgN,
    char* Asm, char* Bsm, int arow_b, int brow_b, int k0, int tid, f32x4 (&acc)[8][4])
{
    s16x8 a[2][4], b0[2][2], b1[2][2];
    // wp0 (A0,B0)
    read_af(Asm, arow_b, k0, 0, a);
    read_bf(Bsm, brow_b, k0, 0, b0);
    __builtin_amdgcn_s_barrier();
    mfma_quad<0, 0>(a, b0, acc);
    if constexpr (W0 >= 0) VMCNT(W0);
    __builtin_amdgcn_s_barrier();
    // wp1 (A0,B1) — A0/B0 LDS regions retired (values live in regs)
    read_bf(Bsm, brow_b, k0, 1, b1);
    if constexpr (STG) {
        stage_region<LDB, true >(AgN, Asm, 0, tid);
        stage_region<LDB, false>(BgN, Bsm, 0, tid);
    }
    __builtin_amdgcn_s_barrier();
    mfma_quad<0, 1>(a, b1, acc);
    if constexpr (W1V >= 0) VMCNT(W1V);
    __builtin_amdgcn_s_barrier();
    // wp2 (A1,B1)
    read_af(Asm, arow_b, k0, 1, a);
    if constexpr (STG) stage_region<LDB, false>(BgN, Bsm, 1, tid);
    __builtin_amdgcn_s_barrier();
    mfma_quad<1, 1>(a, b1, acc);
    __builtin_amdgcn_s_barrier();
    // wp3 (A1,B0) — all operands in regs
    if constexpr (STG) stage_region<LDB, true >(AgN, Asm, 1, tid);
    __builtin_amdgcn_s_barrier();
    mfma_quad<1, 0>(a, b0, acc);
    if constexpr (WEND >= 0) VMCNT(WEND);
    __builtin_amdgcn_s_barrier();
}

template<int LDB>
__device__ __forceinline__ void gemm_mainloop(const char* Ag, const char* Bg,
    char* smem, int KT, int tid, int arow_b, int brow_b, int k0, f32x4 (&acc)[8][4])
{
    char* Asm = smem;
    char* Bsm = smem + 32768;
    // prologue: one window. Issue order A0,B0,B1,A1 so vmcnt(4) lands A0B0.
    stage_region<LDB, true >(Ag, Asm, 0, tid);
    stage_region<LDB, false>(Bg, Bsm, 0, tid);
    stage_region<LDB, false>(Bg, Bsm, 1, tid);
    stage_region<LDB, true >(Ag, Asm, 1, tid);
    VMCNT(4);
    __builtin_amdgcn_s_barrier();

    for (int kt = 0; kt + 1 < KT; ++kt)
        gwindow<LDB, true, 2, 4, 4>(Ag + (size_t)(kt + 1) * 128, Bg + (size_t)(kt + 1) * 128,
            Asm, Bsm, arow_b, brow_b, k0, tid, acc);
    gwindow<LDB, false, 2, 0, -1>(Ag, Bg, Asm, Bsm, arow_b, brow_b, k0, tid, acc);
}

// ---------------------------------------------------------------------------
// Kernel 1: G = gelu(Xb @ W1[e] + b1[e]) -> bf16
// XCD mapping (R6, FETCH 71MB): xcd=L&7; per XCD: sorted same-expert
// sentences; nt varies fastest within a 4-wide band per residency round.
// ---------------------------------------------------------------------------
__global__ __launch_bounds__(512, 4) void moe_gemm1(
    const unsigned short* __restrict__ Xb,
    const int*   __restrict__ labels,
    const int*   __restrict__ perm,
    const unsigned short* __restrict__ W1T,  // [E][FFN][HID]
    const float* __restrict__ B1,
    unsigned short* __restrict__ G)
{
    extern __shared__ char smem[];
    const int L = blockIdx.x;
    const int xcd  = L & 7;
    const int r    = L >> 8;          // band 0..2
    const int i    = (L >> 3) & 31;   // slot within band on this XCD
    const int pair = i >> 2;          // 0..7
    const int bs = perm[xcd * 4 + (pair >> 1)];
    const int mt = pair & 1;
    const int nt = r * 4 + (i & 3);
    const int e  = labels[bs];

    const char* Ag = (const char*)(Xb + ((size_t)bs * SEQ + (size_t)mt * 256) * HID);
    const char* Bg = (const char*)(W1T + (size_t)e * FFN * HID + (size_t)nt * 256 * HID);

    const int tid = threadIdx.x;
    const int lane = tid & 63, w = tid >> 6;
    const int wm = (w >> 2) * 128, wn = (w & 3) * 64;
    const int fr = lane & 15, fq = lane >> 4;
    const int arow_b = (wm + fr) * 128, brow_b = (wn + fr) * 128;
    const int k0 = (fq * 16) ^ ((fr & 7) << 4);

    f32x4 acc[8][4];
#pragma unroll
    for (int i2 = 0; i2 < 8; i2++)
#pragma unroll
        for (int j = 0; j < 4; j++) acc[i2][j] = (f32x4)0.0f;

    gemm_mainloop<HID * 2>(Ag, Bg, smem, HID / 64, tid, arow_b, brow_b, k0, acc);

    const float* b1g = B1 + (size_t)e * FFN + (size_t)nt * 256;
    unsigned short* Cg = G + ((size_t)bs * SEQ + (size_t)mt * 256) * FFN + (size_t)nt * 256;
    float bias[4];
#pragma unroll
    for (int nj = 0; nj < 4; nj++) bias[nj] = b1g[wn + nj * 16 + fr];
#pragma unroll
    for (int mi = 0; mi < 8; mi++)
#pragma unroll
        for (int nj = 0; nj < 4; nj++) {
            const int col = wn + nj * 16 + fr;
#pragma unroll
            for (int rr2 = 0; rr2 < 4; rr2++) {
                const int row = wm + mi * 16 + fq * 4 + rr2;
                float v = acc[mi][nj][rr2] + bias[nj];
                Cg[(size_t)row * FFN + col] = f2bf(gelu_fast(v));
            }
        }
}

// ---------------------------------------------------------------------------
// Kernel 2: Out = G @ W2[e] + b2[e] -> fp32
// ---------------------------------------------------------------------------
__global__ __launch_bounds__(512, 4) void moe_gemm2(
    const unsigned short* __restrict__ G,
    const int*   __restrict__ labels,
    const int*   __restrict__ perm,
    const unsigned short* __restrict__ W2T,  // [E][HID][FFN]
    const float* __restrict__ B2,
    float* __restrict__ Out)
{
    extern __shared__ char smem[];
    const int L = blockIdx.x;
    const int xcd = L & 7, s = L >> 3;       // s in [0,24)
    const int bs = perm[xcd * 4 + s / 6];
    const int rr = s % 6;
    const int mt = rr / 3, nt = rr % 3;
    const int e  = labels[bs];

    const char* Ag = (const char*)(G + ((size_t)bs * SEQ + (size_t)mt * 256) * FFN);
    const char* Bg = (const char*)(W2T + (size_t)e * HID * FFN + (size_t)nt * 256 * FFN);

    const int tid = threadIdx.x;
    const int lane = tid & 63, w = tid >> 6;
    const int wm = (w >> 2) * 128, wn = (w & 3) * 64;
    const int fr = lane & 15, fq = lane >> 4;
    const int arow_b = (wm + fr) * 128, brow_b = (wn + fr) * 128;
    const int k0 = (fq * 16) ^ ((fr & 7) << 4);

    f32x4 acc[8][4];
#pragma unroll
    for (int i = 0; i < 8; i++)
#pragma unroll
        for (int j = 0; j < 4; j++) acc[i][j] = (f32x4)0.0f;

    gemm_mainloop<FFN * 2>(Ag, Bg, smem, FFN / 64, tid, arow_b, brow_b, k0, acc);

    const float* b2g = B2 + (size_t)e * HID + (size_t)nt * 256;
    float* Cg = Out + ((size_t)bs * SEQ + (size_t)mt * 256) * HID + (size_t)nt * 256;
    float bias[4];
#pragma unroll
    for (int nj = 0; nj < 4; nj++) bias[nj] = b2g[wn + nj * 16 + fr];
#pragma unroll
    for (int mi = 0; mi < 8; mi++)
#pragma unroll
        for (int nj = 0; nj < 4; nj++) {
            const int col = wn + nj * 16 + fr;
#pragma unroll
            for (int r = 0; r < 4; r++) {
                const int row = wm + mi * 16 + fq * 4 + r;
                Cg[(size_t)row * HID + col] = acc[mi][nj][r] + bias[nj];
            }
        }
}

extern "C" void kernel_launch(void* const* d_in, const int* in_sizes, int n_in,
                              void* d_out, int out_size, void* d_ws, size_t ws_size,
                              hipStream_t stream) {
    const float* X      = (const float*)d_in[0];
    const int*   labels = (const int*)  d_in[1];
    const float* W1     = (const float*)d_in[2];
    const float* B1     = (const float*)d_in[3];
    const float* W2     = (const float*)d_in[4];
    const float* B2     = (const float*)d_in[5];
    float* Out = (float*)d_out;

    char* ws = (char*)d_ws;
    unsigned short* Xb  = (unsigned short*)(ws);               // 25,165,824 B
    unsigned short* W1T = (unsigned short*)(ws + 25165824);    // 37,748,736 B
    unsigned short* W2T = (unsigned short*)(ws + 62914560);    // 37,748,736 B
    unsigned short* G   = (unsigned short*)(ws + 100663296);   // 100,663,296 B
    int*            perm = (int*)(ws + 201326592);             // 128 B

    (void)hipFuncSetAttribute((const void*)moe_gemm1,
        hipFuncAttributeMaxDynamicSharedMemorySize, 65536);
    (void)hipFuncSetAttribute((const void*)moe_gemm2,
        hipFuncAttributeMaxDynamicSharedMemorySize, 65536);

    sort_labels_kernel<<<1, 64, 0, stream>>>(labels, perm);
    cvt_x_kernel<<<2048, 256, 0, stream>>>(X, Xb, NB * SEQ * HID / 8);
    cvt_transpose_kernel<<<dim3(FFN / 64, HID / 64, NEXP), 256, 0, stream>>>(W1, W1T, HID, FFN);
    cvt_transpose_kernel<<<dim3(HID / 64, FFN / 64, NEXP), 256, 0, stream>>>(W2, W2T, FFN, HID);

    moe_gemm1<<<768, dim3(512), 65536, stream>>>(Xb, labels, perm, W1T, B1, G);
    moe_gemm2<<<192, dim3(512), 65536, stream>>>(G, labels, perm, W2T, B2, Out);
}

// Round 8
// 316.579 us; speedup vs baseline: 5.4905x; 5.4905x over previous
//
#include <hip/hip_runtime.h>
#include <hip/hip_bf16.h>

#define NB   32
#define SEQ  512
#define HID  768
#define FFN  3072
#define NEXP 8

typedef float f32x4 __attribute__((ext_vector_type(4)));
typedef short s16x8 __attribute__((ext_vector_type(8)));

__device__ __forceinline__ unsigned short f2bf(float f) {
    return __builtin_bit_cast(unsigned short, (__bf16)f);
}

__device__ __forceinline__ float fast_exp2(float x) {
    float r; asm("v_exp_f32 %0, %1" : "=v"(r) : "v"(x)); return r;
}
__device__ __forceinline__ float fast_rcp(float x) {
    float r; asm("v_rcp_f32 %0, %1" : "=v"(r) : "v"(x)); return r;
}

// tanh-gelu, overflow-free (exp2 arg <= 0). |error| vs exact-erf gelu ~2e-4.
__device__ __forceinline__ float gelu_fast(float v) {
    float u  = v * (0.7978845608f + 0.0356774081f * v * v);
    float t  = fast_exp2(-2.8853900817779268f * fabsf(u));   // e^{-2|u|}
    float T  = (1.0f - t) * fast_rcp(1.0f + t);              // tanh(|u|)
    return 0.5f * v + 0.5f * fabsf(v) * T;
}

#define GLOAD16(gp, lp) __builtin_amdgcn_global_load_lds( \
    (const __attribute__((address_space(1))) unsigned int*)(gp), \
    (__attribute__((address_space(3))) unsigned int*)(lp), 16, 0, 0)

#define VMCNT(N) asm volatile("s_waitcnt vmcnt(%0)" :: "i"(N) : "memory")

// ---------------------------------------------------------------------------
// stable counting-sort permutation of sentences by expert label (1 wave)
// ---------------------------------------------------------------------------
__global__ void sort_labels_kernel(const int* __restrict__ labels, int* __restrict__ perm)
{
    int i = threadIdx.x;
    if (i < NB) {
        int li = labels[i];
        int rank = 0;
        for (int j = 0; j < NB; j++) {
            int lj = labels[j];
            if (lj < li || (lj == li && j < i)) rank++;
        }
        perm[rank] = i;
    }
}

// ---------------------------------------------------------------------------
// convert X fp32 -> bf16
// ---------------------------------------------------------------------------
__global__ __launch_bounds__(256) void cvt_x_kernel(
    const float* __restrict__ X, unsigned short* __restrict__ Xb, int n8)
{
    int idx = blockIdx.x * blockDim.x + threadIdx.x;
    int stride = gridDim.x * blockDim.x;
    for (int i = idx; i < n8; i += stride) {
        f32x4 a = *(const f32x4*)(X + (size_t)i * 8);
        f32x4 b = *(const f32x4*)(X + (size_t)i * 8 + 4);
        unsigned short o[8];
#pragma unroll
        for (int v = 0; v < 4; v++) o[v] = f2bf(a[v]);
#pragma unroll
        for (int v = 0; v < 4; v++) o[4 + v] = f2bf(b[v]);
        *(s16x8*)(Xb + (size_t)i * 8) = *(s16x8*)o;
    }
}

// ---------------------------------------------------------------------------
// convert + transpose: in [R][C] fp32 -> out [C][R] bf16 per slab
// ---------------------------------------------------------------------------
__global__ __launch_bounds__(256) void cvt_transpose_kernel(
    const float* __restrict__ W, unsigned short* __restrict__ WT, int R, int C)
{
    __shared__ unsigned short tile[64][65];
    const int cb = blockIdx.x * 64, rb = blockIdx.y * 64;
    const float* src = W + (size_t)blockIdx.z * R * C;
    unsigned short* dst = WT + (size_t)blockIdx.z * R * C;
    const int x = threadIdx.x & 63, y0 = threadIdx.x >> 6;
#pragma unroll
    for (int i = 0; i < 16; i++) {
        int r = y0 + i * 4;
        tile[r][x] = f2bf(src[(size_t)(rb + r) * C + cb + x]);
    }
    __syncthreads();
#pragma unroll
    for (int i = 0; i < 16; i++) {
        int c = y0 + i * 4;
        dst[(size_t)(cb + c) * R + rb + x] = tile[x][c];
    }
}

// ---------------------------------------------------------------------------
// 256x128 4-phase RING GEMM. BK=64, 8 waves (4M x 2N, wave-tile 64x64),
// acc[4][4]=64 regs -> fits __launch_bounds__(512,4) => 2 blocks/CU.
// LDS ring 48 KB: A = smem[0..32K) (256 rows x 128 B), B = smem+32K (128 rows).
// Regions by row bit5: A-half h = rows {64k + h*32 + 0..31}, 16 KB (2 ld/thr);
// B-half h analogous within 128 rows, 8 KB (1 ld/thr). Swizzle both sides.
//
// Window t (frag-persistent; 16 ds_read_b128 + 6 gload/thread):
//   wp0 (Alo,Blo): read a(4),b0(4);                          VMCNT(2) bar
//   wp1 (Alo,Bhi): read b1(4); stage Alo,Blo(t+1) [3 ld];    VMCNT(3) bar
//   wp2 (Ahi,Bhi): read a(4);  stage Bhi(t+1)    [1 ld];             bar
//   wp3 (Ahi,Blo): regs only;  stage Ahi(t+1)    [2 ld];     VMCNT(3) bar
// Guards (per-thread outstanding): end-wp0 waits Bhi(t) (leaves wp3's 2);
// end-wp1 waits Ahi(t) (leaves wp1's 3); end-wp3 waits Alo/Blo(t+1)
// (leaves wp2:1 + wp3:2). Never 0 mid-loop. Last window: (2, 0, none).
// ---------------------------------------------------------------------------
template<int LDB>
__device__ __forceinline__ void stage_A(const char* g, char* lds, int half, int tid)
{
#pragma unroll
    for (int p = 0; p < 2; p++) {
        int L  = p * 8192 + tid * 16;
        int rr = L >> 7;                  // 0..127
        int cb = L & 127;
        int row = (rr & 31) + ((rr >> 5) << 6) + half * 32;   // bit5 = half
        int cbs = cb ^ ((row & 7) << 4);
        GLOAD16(g + (size_t)row * LDB + cbs, lds + (size_t)row * 128 + cb);
    }
}
template<int LDB>
__device__ __forceinline__ void stage_B(const char* g, char* lds, int half, int tid)
{
    int L  = tid * 16;
    int rr = L >> 7;                      // 0..63
    int cb = L & 127;
    int row = (rr & 31) + ((rr >> 5) << 6) + half * 32;       // 0..127, bit5=half
    int cbs = cb ^ ((row & 7) << 4);
    GLOAD16(g + (size_t)row * LDB + cbs, lds + (size_t)row * 128 + cb);
}

__device__ __forceinline__ void read_fr(const char* base, int row_b, int k0, int h, s16x8 (&f)[2][2])
{
    const int k1 = k0 ^ 64;
#pragma unroll
    for (int i = 0; i < 2; i++) {
        const char* p = base + row_b + (h * 32 + i * 16) * 128;
        f[0][i] = *(const s16x8*)(p + k0);
        f[1][i] = *(const s16x8*)(p + k1);
    }
}

template<int IH, int JH>
__device__ __forceinline__ void mfma8(s16x8 (&a)[2][2], s16x8 (&b)[2][2], f32x4 (&acc)[4][4])
{
    __builtin_amdgcn_s_setprio(1);
#pragma unroll
    for (int kk = 0; kk < 2; kk++)
#pragma unroll
        for (int i = 0; i < 2; i++)
#pragma unroll
            for (int j = 0; j < 2; j++)
                acc[IH * 2 + i][JH * 2 + j] = __builtin_amdgcn_mfma_f32_16x16x32_bf16(
                    a[kk][i], b[kk][j], acc[IH * 2 + i][JH * 2 + j], 0, 0, 0);
    __builtin_amdgcn_s_setprio(0);
}

template<int LDB, bool STG, int W0, int W1V, int WEND>
__device__ __forceinline__ void gwindow(const char* AgN, const char* BgN,
    char* Asm, char* Bsm, int arow_b, int brow_b, int k0, int tid, f32x4 (&acc)[4][4])
{
    s16x8 a[2][2], b0[2][2], b1[2][2];
    // wp0 (Alo, Blo)
    read_fr(Asm, arow_b, k0, 0, a);
    read_fr(Bsm, brow_b, k0, 0, b0);
    __builtin_amdgcn_s_barrier();
    mfma8<0, 0>(a, b0, acc);
    if constexpr (W0 >= 0) VMCNT(W0);
    __builtin_amdgcn_s_barrier();
    // wp1 (Alo, Bhi)
    read_fr(Bsm, brow_b, k0, 1, b1);
    if constexpr (STG) {
        stage_A<LDB>(AgN, Asm, 0, tid);
        stage_B<LDB>(BgN, Bsm, 0, tid);
    }
    __builtin_amdgcn_s_barrier();
    mfma8<0, 1>(a, b1, acc);
    if constexpr (W1V >= 0) VMCNT(W1V);
    __builtin_amdgcn_s_barrier();
    // wp2 (Ahi, Bhi)
    read_fr(Asm, arow_b, k0, 1, a);
    if constexpr (STG) stage_B<LDB>(BgN, Bsm, 1, tid);
    __builtin_amdgcn_s_barrier();
    mfma8<1, 1>(a, b1, acc);
    __builtin_amdgcn_s_barrier();
    // wp3 (Ahi, Blo) — operands in regs
    if constexpr (STG) stage_A<LDB>(AgN, Asm, 1, tid);
    __builtin_amdgcn_s_barrier();
    mfma8<1, 0>(a, b0, acc);
    if constexpr (WEND >= 0) VMCNT(WEND);
    __builtin_amdgcn_s_barrier();
}

template<int LDB>
__device__ __forceinline__ void gemm_mainloop(const char* Ag, const char* Bg,
    char* smem, int KT, int tid, int arow_b, int brow_b, int k0, f32x4 (&acc)[4][4])
{
    char* Asm = smem;
    char* Bsm = smem + 32768;
    // prologue window 0: issue A-lo(2), B-lo(1), B-hi(1), A-hi(2); wait first 3.
    stage_A<LDB>(Ag, Asm, 0, tid);
    stage_B<LDB>(Bg, Bsm, 0, tid);
    stage_B<LDB>(Bg, Bsm, 1, tid);
    stage_A<LDB>(Ag, Asm, 1, tid);
    VMCNT(3);
    __builtin_amdgcn_s_barrier();

    for (int kt = 0; kt + 1 < KT; ++kt)
        gwindow<LDB, true, 2, 3, 3>(Ag + (size_t)(kt + 1) * 128, Bg + (size_t)(kt + 1) * 128,
            Asm, Bsm, arow_b, brow_b, k0, tid, acc);
    gwindow<LDB, false, 2, 0, -1>(Ag, Bg, Asm, Bsm, arow_b, brow_b, k0, tid, acc);
}

// ---------------------------------------------------------------------------
// Kernel 1: G = gelu(Xb @ W1[e] + b1[e]) -> bf16.  1536 blocks (256x128 tiles)
// ---------------------------------------------------------------------------
__global__ __launch_bounds__(512, 4) void moe_gemm1(
    const unsigned short* __restrict__ Xb,
    const int*   __restrict__ labels,
    const int*   __restrict__ perm,
    const unsigned short* __restrict__ W1T,  // [E][FFN][HID]
    const float* __restrict__ B1,
    unsigned short* __restrict__ G)
{
    extern __shared__ char smem[];
    const int L = blockIdx.x;
    const int xcd = L & 7, s = L >> 3;       // s in [0,192)
    const int bs = perm[xcd * 4 + s / 48];
    const int rr = s % 48;
    const int mt = rr / 24, nt = rr % 24;
    const int e  = labels[bs];

    const char* Ag = (const char*)(Xb + ((size_t)bs * SEQ + (size_t)mt * 256) * HID);
    const char* Bg = (const char*)(W1T + (size_t)e * FFN * HID + (size_t)nt * 128 * HID);

    const int tid = threadIdx.x;
    const int lane = tid & 63, w = tid >> 6;
    const int wm = (w >> 1) * 64, wn = (w & 1) * 64;
    const int fr = lane & 15, fq = lane >> 4;
    const int arow_b = (wm + fr) * 128, brow_b = (wn + fr) * 128;
    const int k0 = (fq * 16) ^ ((fr & 7) << 4);

    f32x4 acc[4][4];
#pragma unroll
    for (int i = 0; i < 4; i++)
#pragma unroll
        for (int j = 0; j < 4; j++) acc[i][j] = (f32x4)0.0f;

    gemm_mainloop<HID * 2>(Ag, Bg, smem, HID / 64, tid, arow_b, brow_b, k0, acc);

    const float* b1g = B1 + (size_t)e * FFN + (size_t)nt * 128;
    unsigned short* Cg = G + ((size_t)bs * SEQ + (size_t)mt * 256) * FFN + (size_t)nt * 128;
    float bias[4];
#pragma unroll
    for (int nj = 0; nj < 4; nj++) bias[nj] = b1g[wn + nj * 16 + fr];
#pragma unroll
    for (int mi = 0; mi < 4; mi++)
#pragma unroll
        for (int nj = 0; nj < 4; nj++) {
            const int col = wn + nj * 16 + fr;
#pragma unroll
            for (int r2 = 0; r2 < 4; r2++) {
                const int row = wm + mi * 16 + fq * 4 + r2;
                float v = acc[mi][nj][r2] + bias[nj];
                Cg[(size_t)row * FFN + col] = f2bf(gelu_fast(v));
            }
        }
}

// ---------------------------------------------------------------------------
// Kernel 2: Out = G @ W2[e] + b2[e] -> fp32.  384 blocks (256x128 tiles)
// ---------------------------------------------------------------------------
__global__ __launch_bounds__(512, 4) void moe_gemm2(
    const unsigned short* __restrict__ G,
    const int*   __restrict__ labels,
    const int*   __restrict__ perm,
    const unsigned short* __restrict__ W2T,  // [E][HID][FFN]
    const float* __restrict__ B2,
    float* __restrict__ Out)
{
    extern __shared__ char smem[];
    const int L = blockIdx.x;
    const int xcd = L & 7, s = L >> 3;       // s in [0,48)
    const int bs = perm[xcd * 4 + s / 12];
    const int rr = s % 12;
    const int mt = rr / 6, nt = rr % 6;
    const int e  = labels[bs];

    const char* Ag = (const char*)(G + ((size_t)bs * SEQ + (size_t)mt * 256) * FFN);
    const char* Bg = (const char*)(W2T + (size_t)e * HID * FFN + (size_t)nt * 128 * FFN);

    const int tid = threadIdx.x;
    const int lane = tid & 63, w = tid >> 6;
    const int wm = (w >> 1) * 64, wn = (w & 1) * 64;
    const int fr = lane & 15, fq = lane >> 4;
    const int arow_b = (wm + fr) * 128, brow_b = (wn + fr) * 128;
    const int k0 = (fq * 16) ^ ((fr & 7) << 4);

    f32x4 acc[4][4];
#pragma unroll
    for (int i = 0; i < 4; i++)
#pragma unroll
        for (int j = 0; j < 4; j++) acc[i][j] = (f32x4)0.0f;

    gemm_mainloop<FFN * 2>(Ag, Bg, smem, FFN / 64, tid, arow_b, brow_b, k0, acc);

    const float* b2g = B2 + (size_t)e * HID + (size_t)nt * 128;
    float* Cg = Out + ((size_t)bs * SEQ + (size_t)mt * 256) * HID + (size_t)nt * 128;
    float bias[4];
#pragma unroll
    for (int nj = 0; nj < 4; nj++) bias[nj] = b2g[wn + nj * 16 + fr];
#pragma unroll
    for (int mi = 0; mi < 4; mi++)
#pragma unroll
        for (int nj = 0; nj < 4; nj++) {
            const int col = wn + nj * 16 + fr;
#pragma unroll
            for (int r2 = 0; r2 < 4; r2++) {
                const int row = wm + mi * 16 + fq * 4 + r2;
                Cg[(size_t)row * HID + col] = acc[mi][nj][r2] + bias[nj];
            }
        }
}

extern "C" void kernel_launch(void* const* d_in, const int* in_sizes, int n_in,
                              void* d_out, int out_size, void* d_ws, size_t ws_size,
                              hipStream_t stream) {
    const float* X      = (const float*)d_in[0];
    const int*   labels = (const int*)  d_in[1];
    const float* W1     = (const float*)d_in[2];
    const float* B1     = (const float*)d_in[3];
    const float* W2     = (const float*)d_in[4];
    const float* B2     = (const float*)d_in[5];
    float* Out = (float*)d_out;

    char* ws = (char*)d_ws;
    unsigned short* Xb  = (unsigned short*)(ws);               // 25,165,824 B
    unsigned short* W1T = (unsigned short*)(ws + 25165824);    // 37,748,736 B
    unsigned short* W2T = (unsigned short*)(ws + 62914560);    // 37,748,736 B
    unsigned short* G   = (unsigned short*)(ws + 100663296);   // 100,663,296 B
    int*            perm = (int*)(ws + 201326592);             // 128 B

    (void)hipFuncSetAttribute((const void*)moe_gemm1,
        hipFuncAttributeMaxDynamicSharedMemorySize, 49152);
    (void)hipFuncSetAttribute((const void*)moe_gemm2,
        hipFuncAttributeMaxDynamicSharedMemorySize, 49152);

    sort_labels_kernel<<<1, 64, 0, stream>>>(labels, perm);
    cvt_x_kernel<<<2048, 256, 0, stream>>>(X, Xb, NB * SEQ * HID / 8);
    cvt_transpose_kernel<<<dim3(FFN / 64, HID / 64, NEXP), 256, 0, stream>>>(W1, W1T, HID, FFN);
    cvt_transpose_kernel<<<dim3(HID / 64, FFN / 64, NEXP), 256, 0, stream>>>(W2, W2T, FFN, HID);

    moe_gemm1<<<1536, dim3(512), 49152, stream>>>(Xb, labels, perm, W1T, B1, G);
    moe_gemm2<<<384,  dim3(512), 49152, stream>>>(G, labels, perm, W2T, B2, Out);
}

// Round 9
// 259.338 us; speedup vs baseline: 6.7024x; 1.2207x over previous
//
#include <hip/hip_runtime.h>
#include <hip/hip_bf16.h>

#define NB   32
#define SEQ  512
#define HID  768
#define FFN  3072
#define NEXP 8

typedef float f32x4 __attribute__((ext_vector_type(4)));
typedef short s16x8 __attribute__((ext_vector_type(8)));

__device__ __forceinline__ unsigned short f2bf(float f) {
    return __builtin_bit_cast(unsigned short, (__bf16)f);
}

__device__ __forceinline__ float fast_exp2(float x) {
    float r; asm("v_exp_f32 %0, %1" : "=v"(r) : "v"(x)); return r;
}
__device__ __forceinline__ float fast_rcp(float x) {
    float r; asm("v_rcp_f32 %0, %1" : "=v"(r) : "v"(x)); return r;
}

// tanh-gelu, overflow-free (exp2 arg <= 0). |error| vs exact-erf gelu ~2e-4.
__device__ __forceinline__ float gelu_fast(float v) {
    float u  = v * (0.7978845608f + 0.0356774081f * v * v);
    float t  = fast_exp2(-2.8853900817779268f * fabsf(u));
    float T  = (1.0f - t) * fast_rcp(1.0f + t);
    return 0.5f * v + 0.5f * fabsf(v) * T;
}

#define GLOAD16(gp, lp) __builtin_amdgcn_global_load_lds( \
    (const __attribute__((address_space(1))) unsigned int*)(gp), \
    (__attribute__((address_space(3))) unsigned int*)(lp), 16, 0, 0)

#define VMCNT(N) asm volatile("s_waitcnt vmcnt(%0)" :: "i"(N) : "memory")

// ---------------------------------------------------------------------------
// stable counting-sort permutation of sentences by expert label (1 wave)
// ---------------------------------------------------------------------------
__global__ void sort_labels_kernel(const int* __restrict__ labels, int* __restrict__ perm)
{
    int i = threadIdx.x;
    if (i < NB) {
        int li = labels[i];
        int rank = 0;
        for (int j = 0; j < NB; j++) {
            int lj = labels[j];
            if (lj < li || (lj == li && j < i)) rank++;
        }
        perm[rank] = i;
    }
}

// ---------------------------------------------------------------------------
// convert X fp32 -> bf16
// ---------------------------------------------------------------------------
__global__ __launch_bounds__(256) void cvt_x_kernel(
    const float* __restrict__ X, unsigned short* __restrict__ Xb, int n8)
{
    int idx = blockIdx.x * blockDim.x + threadIdx.x;
    int stride = gridDim.x * blockDim.x;
    for (int i = idx; i < n8; i += stride) {
        f32x4 a = *(const f32x4*)(X + (size_t)i * 8);
        f32x4 b = *(const f32x4*)(X + (size_t)i * 8 + 4);
        unsigned short o[8];
#pragma unroll
        for (int v = 0; v < 4; v++) o[v] = f2bf(a[v]);
#pragma unroll
        for (int v = 0; v < 4; v++) o[4 + v] = f2bf(b[v]);
        *(s16x8*)(Xb + (size_t)i * 8) = *(s16x8*)o;
    }
}

// ---------------------------------------------------------------------------
// convert + transpose: in [R][C] fp32 -> out [C][R] bf16 per slab
// ---------------------------------------------------------------------------
__global__ __launch_bounds__(256) void cvt_transpose_kernel(
    const float* __restrict__ W, unsigned short* __restrict__ WT, int R, int C)
{
    __shared__ unsigned short tile[64][65];
    const int cb = blockIdx.x * 64, rb = blockIdx.y * 64;
    const float* src = W + (size_t)blockIdx.z * R * C;
    unsigned short* dst = WT + (size_t)blockIdx.z * R * C;
    const int x = threadIdx.x & 63, y0 = threadIdx.x >> 6;
#pragma unroll
    for (int i = 0; i < 16; i++) {
        int r = y0 + i * 4;
        tile[r][x] = f2bf(src[(size_t)(rb + r) * C + cb + x]);
    }
    __syncthreads();
#pragma unroll
    for (int i = 0; i < 16; i++) {
        int c = y0 + i * 4;
        dst[(size_t)(cb + c) * R + rb + x] = tile[x][c];
    }
}

// ===========================================================================
// GEMM1: producer/consumer wave-specialized ring GEMM.
// 256x128 tile, BK=32, 9 waves: 8 consumers (64x64 wave-tiles) + 1 producer.
// LDS ring: 4 slots x 24 KB (A 16 KB: 256 rows x 64 B; B 8 KB: 128 x 64 B).
// Swizzle (BK=32, 64-B rows): col_byte ^= ((row>>1)&3)<<4 — both sides.
// Slot k (between barriers k-1,k):
//   producer: issue batch k+2 (24 gload16); vmcnt(48) [tail 24/0] ensures
//             batch k landed; s_barrier. Consumers NEVER vmcnt.
//   consumers: compute window k-1 (8 ds_read_b128 + 16 MFMA); __syncthreads.
// Ring safety: writes (k+2)%4, reads (k-1)%4 — spacing 3 of 4. In-order
// vmcnt retirement (m135) makes the counted guards exact.
// ===========================================================================
__global__ __launch_bounds__(576, 3) void moe_gemm1(
    const unsigned short* __restrict__ Xb,
    const int*   __restrict__ labels,
    const int*   __restrict__ perm,
    const unsigned short* __restrict__ W1T,  // [E][FFN][HID]
    const float* __restrict__ B1,
    unsigned short* __restrict__ G)
{
    extern __shared__ char smem[];
    const int L = blockIdx.x;
    const int xcd = L & 7, s = L >> 3;       // s in [0,192)
    const int bs = perm[xcd * 4 + s / 48];
    const int rr = s % 48;
    const int mt = rr / 24, nt = rr % 24;
    const int e  = labels[bs];

    const char* Ag = (const char*)(Xb + ((size_t)bs * SEQ + (size_t)mt * 256) * HID);
    const char* Bg = (const char*)(W1T + (size_t)e * FFN * HID + (size_t)nt * 128 * HID);

    const int tid  = threadIdx.x;
    const int wid  = tid >> 6, lane = tid & 63;
    const int KT   = HID / 32;               // 24 windows

    if (wid == 8) {
        // ------------------------- PRODUCER -------------------------
        const int r4  = lane >> 2;           // 0..15
        const int ch  = (lane & 3) * 16;     // 16B chunk in 64B row
        for (int k = 0; k < KT; ++k) {
            if (k == 0) {                    // prologue: batches 0,1
#pragma unroll
                for (int w = 0; w < 2; w++) {
                    char* slot = smem + (w & 3) * 24576;
                    const char* ga = Ag + w * 64;
                    const char* gb = Bg + w * 64;
#pragma unroll
                    for (int i = 0; i < 16; i++) {
                        int row = i * 16 + r4;
                        int src = ch ^ (((row >> 1) & 3) << 4);
                        GLOAD16(ga + (size_t)row * (HID * 2) + src, slot + i * 1024 + lane * 16);
                    }
#pragma unroll
                    for (int i = 0; i < 8; i++) {
                        int row = i * 16 + r4;
                        int src = ch ^ (((row >> 1) & 3) << 4);
                        GLOAD16(gb + (size_t)row * (HID * 2) + src, slot + 16384 + i * 1024 + lane * 16);
                    }
                }
            }
            if (k + 2 < KT) {
                int w = k + 2;
                char* slot = smem + (w & 3) * 24576;
                const char* ga = Ag + w * 64;
                const char* gb = Bg + w * 64;
#pragma unroll
                for (int i = 0; i < 16; i++) {
                    int row = i * 16 + r4;
                    int src = ch ^ (((row >> 1) & 3) << 4);
                    GLOAD16(ga + (size_t)row * (HID * 2) + src, slot + i * 1024 + lane * 16);
                }
#pragma unroll
                for (int i = 0; i < 8; i++) {
                    int row = i * 16 + r4;
                    int src = ch ^ (((row >> 1) & 3) << 4);
                    GLOAD16(gb + (size_t)row * (HID * 2) + src, slot + 16384 + i * 1024 + lane * 16);
                }
                VMCNT(48);                   // 3 batches in flight -> batch k landed
            } else if (k + 1 < KT) {
                VMCNT(24);                   // 2 in flight -> batch k landed
            } else {
                VMCNT(0);                    // last batch
            }
            __builtin_amdgcn_s_barrier();
        }
        return;
    }

    // --------------------------- CONSUMERS ---------------------------
    const int fr = lane & 15, fq = lane >> 4;
    const int wm = (wid >> 1) * 64, wn = (wid & 1) * 64;

    int aoff[4], boff[4];
#pragma unroll
    for (int i = 0; i < 4; i++) {
        int arow = wm + i * 16 + fr;
        aoff[i] = arow * 64 + ((fq * 16) ^ (((arow >> 1) & 3) << 4));
        int brow = wn + i * 16 + fr;
        boff[i] = 16384 + brow * 64 + ((fq * 16) ^ (((brow >> 1) & 3) << 4));
    }

    f32x4 acc[4][4];
#pragma unroll
    for (int i = 0; i < 4; i++)
#pragma unroll
        for (int j = 0; j < 4; j++) acc[i][j] = (f32x4)0.0f;

    for (int k = 0; k < KT; ++k) {
        if (k > 0) {
            const char* slot = smem + ((k - 1) & 3) * 24576;
            s16x8 av[4], bv[4];
#pragma unroll
            for (int i = 0; i < 4; i++) av[i] = *(const s16x8*)(slot + aoff[i]);
#pragma unroll
            for (int j = 0; j < 4; j++) bv[j] = *(const s16x8*)(slot + boff[j]);
            __builtin_amdgcn_s_setprio(1);
#pragma unroll
            for (int i = 0; i < 4; i++)
#pragma unroll
                for (int j = 0; j < 4; j++)
                    acc[i][j] = __builtin_amdgcn_mfma_f32_16x16x32_bf16(av[i], bv[j], acc[i][j], 0, 0, 0);
            __builtin_amdgcn_s_setprio(0);
        }
        __syncthreads();
    }
    {   // final window KT-1 (landed before last barrier)
        const char* slot = smem + ((KT - 1) & 3) * 24576;
        s16x8 av[4], bv[4];
#pragma unroll
        for (int i = 0; i < 4; i++) av[i] = *(const s16x8*)(slot + aoff[i]);
#pragma unroll
        for (int j = 0; j < 4; j++) bv[j] = *(const s16x8*)(slot + boff[j]);
#pragma unroll
        for (int i = 0; i < 4; i++)
#pragma unroll
            for (int j = 0; j < 4; j++)
                acc[i][j] = __builtin_amdgcn_mfma_f32_16x16x32_bf16(av[i], bv[j], acc[i][j], 0, 0, 0);
    }

    const float* b1g = B1 + (size_t)e * FFN + (size_t)nt * 128;
    unsigned short* Cg = G + ((size_t)bs * SEQ + (size_t)mt * 256) * FFN + (size_t)nt * 128;
    float bias[4];
#pragma unroll
    for (int nj = 0; nj < 4; nj++) bias[nj] = b1g[wn + nj * 16 + fr];
#pragma unroll
    for (int mi = 0; mi < 4; mi++)
#pragma unroll
        for (int nj = 0; nj < 4; nj++) {
            const int col = wn + nj * 16 + fr;
#pragma unroll
            for (int r2 = 0; r2 < 4; r2++) {
                const int row = wm + mi * 16 + fq * 4 + r2;
                float v = acc[mi][nj][r2] + bias[nj];
                Cg[(size_t)row * FFN + col] = f2bf(gelu_fast(v));
            }
        }
}

// ===========================================================================
// GEMM2: proven R5 256x256 8-phase dbuf structure (54 µs class).
// ===========================================================================
template<int LDB, bool ISA>
__device__ __forceinline__ void stage_region(const char* g, char* lds, int half, int tid)
{
#pragma unroll
    for (int p = 0; p < 2; p++) {
        int L  = p * 8192 + tid * 16;
        int rr = L >> 7;
        int cb = L & 127;
        int row = ISA ? ((rr & 63) + ((rr >> 6) << 7) + half * 64)
                      : ((rr & 31) + ((rr >> 5) << 6) + half * 32);
        int cbs = cb ^ ((row & 7) << 4);
        GLOAD16(g + (size_t)row * LDB + cbs, lds + (size_t)row * 128 + cb);
    }
}

__device__ __forceinline__ void read_af(const char* Ab, int arow_b, int k0, int ih, s16x8 (&a)[2][4])
{
    const int k1 = k0 ^ 64;
#pragma unroll
    for (int i = 0; i < 4; i++) {
        const char* p = Ab + arow_b + (ih * 64 + i * 16) * 128;
        a[0][i] = *(const s16x8*)(p + k0);
        a[1][i] = *(const s16x8*)(p + k1);
    }
}
__device__ __forceinline__ void read_bf(const char* Bb, int brow_b, int k0, int jh, s16x8 (&b)[2][2])
{
    const int k1 = k0 ^ 64;
#pragma unroll
    for (int j = 0; j < 2; j++) {
        const char* p = Bb + brow_b + (jh * 32 + j * 16) * 128;
        b[0][j] = *(const s16x8*)(p + k0);
        b[1][j] = *(const s16x8*)(p + k1);
    }
}

template<int IH, int JH>
__device__ __forceinline__ void mfma_quad(s16x8 (&a)[2][4], s16x8 (&b)[2][2], f32x4 (&acc)[8][4])
{
    __builtin_amdgcn_s_setprio(1);
#pragma unroll
    for (int kk = 0; kk < 2; kk++)
#pragma unroll
        for (int i = 0; i < 4; i++)
#pragma unroll
            for (int j = 0; j < 2; j++)
                acc[IH * 4 + i][JH * 2 + j] = __builtin_amdgcn_mfma_f32_16x16x32_bf16(
                    a[kk][i], b[kk][j], acc[IH * 4 + i][JH * 2 + j], 0, 0, 0);
    __builtin_amdgcn_s_setprio(0);
}

template<int LDB, bool S1, bool S2, int VM>
__device__ __forceinline__ void gwindow(const char* AgK, const char* BgK,
    char* Acur, char* Bcur, char* Anxt, char* Bnxt,
    int arow_b, int brow_b, int k0, int tid, f32x4 (&acc)[8][4])
{
    s16x8 a[2][4], b0[2][2], b1[2][2];
    read_af(Acur, arow_b, k0, 0, a);
    read_bf(Bcur, brow_b, k0, 0, b0);
    if constexpr (S1) stage_region<LDB, true >(AgK + 128, Anxt, 1, tid);
    __builtin_amdgcn_s_barrier();
    mfma_quad<0, 0>(a, b0, acc);
    __builtin_amdgcn_s_barrier();
    read_bf(Bcur, brow_b, k0, 1, b1);
    if constexpr (S1) stage_region<LDB, false>(BgK + 128, Bnxt, 1, tid);
    __builtin_amdgcn_s_barrier();
    mfma_quad<0, 1>(a, b1, acc);
    __builtin_amdgcn_s_barrier();
    read_af(Acur, arow_b, k0, 1, a);
    if constexpr (S2) stage_region<LDB, true >(AgK + 256, Acur, 0, tid);
    __builtin_amdgcn_s_barrier();
    mfma_quad<1, 1>(a, b1, acc);
    __builtin_amdgcn_s_barrier();
    if constexpr (S2) stage_region<LDB, false>(BgK + 256, Bcur, 0, tid);
    __builtin_amdgcn_s_barrier();
    mfma_quad<1, 0>(a, b0, acc);
    if constexpr (VM >= 0) VMCNT(VM);
    __builtin_amdgcn_s_barrier();
}

template<int LDB>
__device__ __forceinline__ void gemm_mainloop(const char* Ag, const char* Bg,
    char* smem, int KT, int tid, int arow_b, int brow_b, int k0, f32x4 (&acc)[8][4])
{
    stage_region<LDB, true >(Ag,       smem,          0, tid);
    stage_region<LDB, false>(Bg,       smem + 65536,  0, tid);
    stage_region<LDB, true >(Ag,       smem,          1, tid);
    stage_region<LDB, false>(Bg,       smem + 65536,  1, tid);
    stage_region<LDB, true >(Ag + 128, smem + 32768,  0, tid);
    stage_region<LDB, false>(Bg + 128, smem + 98304,  0, tid);
    VMCNT(4);
    __builtin_amdgcn_s_barrier();

    int cur = 0;
    for (int kt = 0; kt < KT - 2; ++kt) {
        char* Acur = smem + (cur << 15);
        char* Anxt = smem + ((cur ^ 1) << 15);
        char* Bcur = smem + 65536 + (cur << 15);
        char* Bnxt = smem + 65536 + ((cur ^ 1) << 15);
        gwindow<LDB, true, true, 4>(Ag + (size_t)kt * 128, Bg + (size_t)kt * 128,
            Acur, Bcur, Anxt, Bnxt, arow_b, brow_b, k0, tid, acc);
        cur ^= 1;
    }
    {
        char* Acur = smem + (cur << 15);
        char* Anxt = smem + ((cur ^ 1) << 15);
        char* Bcur = smem + 65536 + (cur << 15);
        char* Bnxt = smem + 65536 + ((cur ^ 1) << 15);
        gwindow<LDB, true, false, 0>(Ag + (size_t)(KT - 2) * 128, Bg + (size_t)(KT - 2) * 128,
            Acur, Bcur, Anxt, Bnxt, arow_b, brow_b, k0, tid, acc);
        cur ^= 1;
    }
    {
        char* Acur = smem + (cur << 15);
        char* Anxt = smem + ((cur ^ 1) << 15);
        char* Bcur = smem + 65536 + (cur << 15);
        char* Bnxt = smem + 65536 + ((cur ^ 1) << 15);
        gwindow<LDB, false, false, -1>(Ag + (size_t)(KT - 1) * 128, Bg + (size_t)(KT - 1) * 128,
            Acur, Bcur, Anxt, Bnxt, arow_b, brow_b, k0, tid, acc);
    }
}

__global__ __launch_bounds__(512, 2) void moe_gemm2(
    const unsigned short* __restrict__ G,
    const int*   __restrict__ labels,
    const int*   __restrict__ perm,
    const unsigned short* __restrict__ W2T,  // [E][HID][FFN]
    const float* __restrict__ B2,
    float* __restrict__ Out)
{
    extern __shared__ char smem[];
    const int L = blockIdx.x;
    const int xcd = L & 7, s = L >> 3;       // s in [0,24)
    const int bs = perm[xcd * 4 + s / 6];
    const int rr = s % 6;
    const int mt = rr / 3, nt = rr % 3;
    const int e  = labels[bs];

    const char* Ag = (const char*)(G + ((size_t)bs * SEQ + (size_t)mt * 256) * FFN);
    const char* Bg = (const char*)(W2T + (size_t)e * HID * FFN + (size_t)nt * 256 * FFN);

    const int tid = threadIdx.x;
    const int lane = tid & 63, w = tid >> 6;
    const int wm = (w >> 2) * 128, wn = (w & 3) * 64;
    const int fr = lane & 15, fq = lane >> 4;
    const int arow_b = (wm + fr) * 128, brow_b = (wn + fr) * 128;
    const int k0 = (fq * 16) ^ ((fr & 7) << 4);

    f32x4 acc[8][4];
#pragma unroll
    for (int i = 0; i < 8; i++)
#pragma unroll
        for (int j = 0; j < 4; j++) acc[i][j] = (f32x4)0.0f;

    gemm_mainloop<FFN * 2>(Ag, Bg, smem, FFN / 64, tid, arow_b, brow_b, k0, acc);

    const float* b2g = B2 + (size_t)e * HID + (size_t)nt * 256;
    float* Cg = Out + ((size_t)bs * SEQ + (size_t)mt * 256) * HID + (size_t)nt * 256;
    float bias[4];
#pragma unroll
    for (int nj = 0; nj < 4; nj++) bias[nj] = b2g[wn + nj * 16 + fr];
#pragma unroll
    for (int mi = 0; mi < 8; mi++)
#pragma unroll
        for (int nj = 0; nj < 4; nj++) {
            const int col = wn + nj * 16 + fr;
#pragma unroll
            for (int r = 0; r < 4; r++) {
                const int row = wm + mi * 16 + fq * 4 + r;
                Cg[(size_t)row * HID + col] = acc[mi][nj][r] + bias[nj];
            }
        }
}

extern "C" void kernel_launch(void* const* d_in, const int* in_sizes, int n_in,
                              void* d_out, int out_size, void* d_ws, size_t ws_size,
                              hipStream_t stream) {
    const float* X      = (const float*)d_in[0];
    const int*   labels = (const int*)  d_in[1];
    const float* W1     = (const float*)d_in[2];
    const float* B1     = (const float*)d_in[3];
    const float* W2     = (const float*)d_in[4];
    const float* B2     = (const float*)d_in[5];
    float* Out = (float*)d_out;

    char* ws = (char*)d_ws;
    unsigned short* Xb  = (unsigned short*)(ws);               // 25,165,824 B
    unsigned short* W1T = (unsigned short*)(ws + 25165824);    // 37,748,736 B
    unsigned short* W2T = (unsigned short*)(ws + 62914560);    // 37,748,736 B
    unsigned short* G   = (unsigned short*)(ws + 100663296);   // 100,663,296 B
    int*            perm = (int*)(ws + 201326592);             // 128 B

    (void)hipFuncSetAttribute((const void*)moe_gemm1,
        hipFuncAttributeMaxDynamicSharedMemorySize, 98304);
    (void)hipFuncSetAttribute((const void*)moe_gemm2,
        hipFuncAttributeMaxDynamicSharedMemorySize, 131072);

    sort_labels_kernel<<<1, 64, 0, stream>>>(labels, perm);
    cvt_x_kernel<<<2048, 256, 0, stream>>>(X, Xb, NB * SEQ * HID / 8);
    cvt_transpose_kernel<<<dim3(FFN / 64, HID / 64, NEXP), 256, 0, stream>>>(W1, W1T, HID, FFN);
    cvt_transpose_kernel<<<dim3(HID / 64, FFN / 64, NEXP), 256, 0, stream>>>(W2, W2T, FFN, HID);

    moe_gemm1<<<1536, dim3(576), 98304, stream>>>(Xb, labels, perm, W1T, B1, G);
    moe_gemm2<<<192,  dim3(512), 131072, stream>>>(G, labels, perm, W2T, B2, Out);
}

// Round 10
// 243.694 us; speedup vs baseline: 7.1327x; 1.0642x over previous
//
#include <hip/hip_runtime.h>
#include <hip/hip_bf16.h>

#define NB   32
#define SEQ  512
#define HID  768
#define FFN  3072
#define NEXP 8

typedef float f32x4 __attribute__((ext_vector_type(4)));
typedef short s16x8 __attribute__((ext_vector_type(8)));

__device__ __forceinline__ unsigned short f2bf(float f) {
    return __builtin_bit_cast(unsigned short, (__bf16)f);
}

__device__ __forceinline__ float fast_exp2(float x) {
    float r; asm("v_exp_f32 %0, %1" : "=v"(r) : "v"(x)); return r;
}
__device__ __forceinline__ float fast_rcp(float x) {
    float r; asm("v_rcp_f32 %0, %1" : "=v"(r) : "v"(x)); return r;
}

// tanh-gelu, overflow-free (exp2 arg <= 0). |error| vs exact-erf gelu ~2e-4.
__device__ __forceinline__ float gelu_fast(float v) {
    float u  = v * (0.7978845608f + 0.0356774081f * v * v);
    float t  = fast_exp2(-2.8853900817779268f * fabsf(u));
    float T  = (1.0f - t) * fast_rcp(1.0f + t);
    return 0.5f * v + 0.5f * fabsf(v) * T;
}

#define GLOAD16(gp, lp) __builtin_amdgcn_global_load_lds( \
    (const __attribute__((address_space(1))) unsigned int*)(gp), \
    (__attribute__((address_space(3))) unsigned int*)(lp), 16, 0, 0)

#define VMCNT(N) asm volatile("s_waitcnt vmcnt(%0)" :: "i"(N) : "memory")

// ---------------------------------------------------------------------------
// stable counting-sort permutation of sentences by expert label (1 wave)
// ---------------------------------------------------------------------------
__global__ void sort_labels_kernel(const int* __restrict__ labels, int* __restrict__ perm)
{
    int i = threadIdx.x;
    if (i < NB) {
        int li = labels[i];
        int rank = 0;
        for (int j = 0; j < NB; j++) {
            int lj = labels[j];
            if (lj < li || (lj == li && j < i)) rank++;
        }
        perm[rank] = i;
    }
}

// ---------------------------------------------------------------------------
// convert X fp32 -> bf16, XCD-aligned with gemm1's consumer mapping:
// block L: xcd = L&7 handles sentences perm[xcd*4 .. +3] (8 slabs each).
// Leaves each XCD's 3 MB of Xb panels L2-warm for gemm1.
// ---------------------------------------------------------------------------
__global__ __launch_bounds__(256) void cvt_x_xcd(
    const float* __restrict__ X, const int* __restrict__ perm,
    unsigned short* __restrict__ Xb)
{
    const int L = blockIdx.x;              // 256 blocks
    const int xcd = L & 7, j = L >> 3;     // j in [0,32)
    const int sent = perm[xcd * 4 + (j >> 3)];
    const int slab = j & 7;
    const size_t base = (size_t)sent * (SEQ * HID) + (size_t)slab * (SEQ * HID / 8);
    const float* src = X + base;
    unsigned short* dst = Xb + base;
    for (int i = threadIdx.x; i < SEQ * HID / 8 / 8; i += 256) {
        f32x4 a = *(const f32x4*)(src + (size_t)i * 8);
        f32x4 b = *(const f32x4*)(src + (size_t)i * 8 + 4);
        unsigned short o[8];
#pragma unroll
        for (int v = 0; v < 4; v++) o[v] = f2bf(a[v]);
#pragma unroll
        for (int v = 0; v < 4; v++) o[4 + v] = f2bf(b[v]);
        *(s16x8*)(dst + (size_t)i * 8) = *(s16x8*)o;
    }
}

// ---------------------------------------------------------------------------
// convert + transpose: in [R][C] fp32 -> out [C][R] bf16 per slab
// ---------------------------------------------------------------------------
__global__ __launch_bounds__(256) void cvt_transpose_kernel(
    const float* __restrict__ W, unsigned short* __restrict__ WT, int R, int C)
{
    __shared__ unsigned short tile[64][65];
    const int cb = blockIdx.x * 64, rb = blockIdx.y * 64;
    const float* src = W + (size_t)blockIdx.z * R * C;
    unsigned short* dst = WT + (size_t)blockIdx.z * R * C;
    const int x = threadIdx.x & 63, y0 = threadIdx.x >> 6;
#pragma unroll
    for (int i = 0; i < 16; i++) {
        int r = y0 + i * 4;
        tile[r][x] = f2bf(src[(size_t)(rb + r) * C + cb + x]);
    }
    __syncthreads();
#pragma unroll
    for (int i = 0; i < 16; i++) {
        int c = y0 + i * 4;
        dst[(size_t)(cb + c) * R + rb + x] = tile[x][c];
    }
}

// ---------------------------------------------------------------------------
// 256x256 8-phase GEMM (BK=64, 8 waves, 2 LDS buffers of 64KB). See R5 notes.
// ---------------------------------------------------------------------------
template<int LDB, bool ISA>
__device__ __forceinline__ void stage_region(const char* g, char* lds, int half, int tid)
{
#pragma unroll
    for (int p = 0; p < 2; p++) {
        int L  = p * 8192 + tid * 16;
        int rr = L >> 7;
        int cb = L & 127;
        int row = ISA ? ((rr & 63) + ((rr >> 6) << 7) + half * 64)
                      : ((rr & 31) + ((rr >> 5) << 6) + half * 32);
        int cbs = cb ^ ((row & 7) << 4);
        GLOAD16(g + (size_t)row * LDB + cbs, lds + (size_t)row * 128 + cb);
    }
}

__device__ __forceinline__ void read_af(const char* Ab, int arow_b, int k0, int ih, s16x8 (&a)[2][4])
{
    const int k1 = k0 ^ 64;
#pragma unroll
    for (int i = 0; i < 4; i++) {
        const char* p = Ab + arow_b + (ih * 64 + i * 16) * 128;
        a[0][i] = *(const s16x8*)(p + k0);
        a[1][i] = *(const s16x8*)(p + k1);
    }
}
__device__ __forceinline__ void read_bf(const char* Bb, int brow_b, int k0, int jh, s16x8 (&b)[2][2])
{
    const int k1 = k0 ^ 64;
#pragma unroll
    for (int j = 0; j < 2; j++) {
        const char* p = Bb + brow_b + (jh * 32 + j * 16) * 128;
        b[0][j] = *(const s16x8*)(p + k0);
        b[1][j] = *(const s16x8*)(p + k1);
    }
}

template<int IH, int JH>
__device__ __forceinline__ void mfma_quad(s16x8 (&a)[2][4], s16x8 (&b)[2][2], f32x4 (&acc)[8][4])
{
    __builtin_amdgcn_s_setprio(1);
#pragma unroll
    for (int kk = 0; kk < 2; kk++)
#pragma unroll
        for (int i = 0; i < 4; i++)
#pragma unroll
            for (int j = 0; j < 2; j++)
                acc[IH * 4 + i][JH * 2 + j] = __builtin_amdgcn_mfma_f32_16x16x32_bf16(
                    a[kk][i], b[kk][j], acc[IH * 4 + i][JH * 2 + j], 0, 0, 0);
    __builtin_amdgcn_s_setprio(0);
}

template<int LDB, bool S1, bool S2, int VM>
__device__ __forceinline__ void gwindow(const char* AgK, const char* BgK,
    char* Acur, char* Bcur, char* Anxt, char* Bnxt,
    int arow_b, int brow_b, int k0, int tid, f32x4 (&acc)[8][4])
{
    s16x8 a[2][4], b0[2][2], b1[2][2];
    read_af(Acur, arow_b, k0, 0, a);
    read_bf(Bcur, brow_b, k0, 0, b0);
    if constexpr (S1) stage_region<LDB, true >(AgK + 128, Anxt, 1, tid);
    __builtin_amdgcn_s_barrier();
    mfma_quad<0, 0>(a, b0, acc);
    __builtin_amdgcn_s_barrier();
    read_bf(Bcur, brow_b, k0, 1, b1);
    if constexpr (S1) stage_region<LDB, false>(BgK + 128, Bnxt, 1, tid);
    __builtin_amdgcn_s_barrier();
    mfma_quad<0, 1>(a, b1, acc);
    __builtin_amdgcn_s_barrier();
    read_af(Acur, arow_b, k0, 1, a);
    if constexpr (S2) stage_region<LDB, true >(AgK + 256, Acur, 0, tid);
    __builtin_amdgcn_s_barrier();
    mfma_quad<1, 1>(a, b1, acc);
    __builtin_amdgcn_s_barrier();
    if constexpr (S2) stage_region<LDB, false>(BgK + 256, Bcur, 0, tid);
    __builtin_amdgcn_s_barrier();
    mfma_quad<1, 0>(a, b0, acc);
    if constexpr (VM >= 0) VMCNT(VM);
    __builtin_amdgcn_s_barrier();
}

template<int LDB>
__device__ __forceinline__ void gemm_mainloop(const char* Ag, const char* Bg,
    char* smem, int KT, int tid, int arow_b, int brow_b, int k0, f32x4 (&acc)[8][4])
{
    stage_region<LDB, true >(Ag,       smem,          0, tid);
    stage_region<LDB, false>(Bg,       smem + 65536,  0, tid);
    stage_region<LDB, true >(Ag,       smem,          1, tid);
    stage_region<LDB, false>(Bg,       smem + 65536,  1, tid);
    stage_region<LDB, true >(Ag + 128, smem + 32768,  0, tid);
    stage_region<LDB, false>(Bg + 128, smem + 98304,  0, tid);
    VMCNT(4);
    __builtin_amdgcn_s_barrier();

    int cur = 0;
    for (int kt = 0; kt < KT - 2; ++kt) {
        char* Acur = smem + (cur << 15);
        char* Anxt = smem + ((cur ^ 1) << 15);
        char* Bcur = smem + 65536 + (cur << 15);
        char* Bnxt = smem + 65536 + ((cur ^ 1) << 15);
        gwindow<LDB, true, true, 4>(Ag + (size_t)kt * 128, Bg + (size_t)kt * 128,
            Acur, Bcur, Anxt, Bnxt, arow_b, brow_b, k0, tid, acc);
        cur ^= 1;
    }
    {
        char* Acur = smem + (cur << 15);
        char* Anxt = smem + ((cur ^ 1) << 15);
        char* Bcur = smem + 65536 + (cur << 15);
        char* Bnxt = smem + 65536 + ((cur ^ 1) << 15);
        gwindow<LDB, true, false, 0>(Ag + (size_t)(KT - 2) * 128, Bg + (size_t)(KT - 2) * 128,
            Acur, Bcur, Anxt, Bnxt, arow_b, brow_b, k0, tid, acc);
        cur ^= 1;
    }
    {
        char* Acur = smem + (cur << 15);
        char* Anxt = smem + ((cur ^ 1) << 15);
        char* Bcur = smem + 65536 + (cur << 15);
        char* Bnxt = smem + 65536 + ((cur ^ 1) << 15);
        gwindow<LDB, false, false, -1>(Ag + (size_t)(KT - 1) * 128, Bg + (size_t)(KT - 1) * 128,
            Acur, Bcur, Anxt, Bnxt, arow_b, brow_b, k0, tid, acc);
    }
}

// ---------------------------------------------------------------------------
// Kernel 1: G = gelu(Xb @ W1[e] + b1[e]) -> bf16
// R6 banding mapping; epilogue via LDS-coalesced FULL-LINE nontemporal stores
// (bypasses L2 without RMW -> stops write-thrash of the A/B read working set).
// ---------------------------------------------------------------------------
__global__ __launch_bounds__(512, 2) void moe_gemm1(
    const unsigned short* __restrict__ Xb,
    const int*   __restrict__ labels,
    const int*   __restrict__ perm,
    const unsigned short* __restrict__ W1T,  // [E][FFN][HID]
    const float* __restrict__ B1,
    unsigned short* __restrict__ G)
{
    extern __shared__ char smem[];
    const int L = blockIdx.x;
    const int xcd  = L & 7;
    const int r    = L >> 8;          // band 0..2
    const int i    = (L >> 3) & 31;
    const int pair = i >> 2;          // 0..7
    const int bs = perm[xcd * 4 + (pair >> 1)];
    const int mt = pair & 1;
    const int nt = r * 4 + (i & 3);
    const int e  = labels[bs];

    const char* Ag = (const char*)(Xb + ((size_t)bs * SEQ + (size_t)mt * 256) * HID);
    const char* Bg = (const char*)(W1T + (size_t)e * FFN * HID + (size_t)nt * 256 * HID);

    const int tid = threadIdx.x;
    const int lane = tid & 63, w = tid >> 6;
    const int wm = (w >> 2) * 128, wn = (w & 3) * 64;
    const int fr = lane & 15, fq = lane >> 4;
    const int arow_b = (wm + fr) * 128, brow_b = (wn + fr) * 128;
    const int k0 = (fq * 16) ^ ((fr & 7) << 4);

    f32x4 acc[8][4];
#pragma unroll
    for (int i2 = 0; i2 < 8; i2++)
#pragma unroll
        for (int j = 0; j < 4; j++) acc[i2][j] = (f32x4)0.0f;

    gemm_mainloop<HID * 2>(Ag, Bg, smem, HID / 64, tid, arow_b, brow_b, k0, acc);

    // ---- epilogue: bias+gelu -> LDS bf16 tile [256][256] (XOR-swizzled) ----
    const float* b1g = B1 + (size_t)e * FFN + (size_t)nt * 256;
    float bias[4];
#pragma unroll
    for (int nj = 0; nj < 4; nj++) bias[nj] = b1g[wn + nj * 16 + fr];
#pragma unroll
    for (int mi = 0; mi < 8; mi++)
#pragma unroll
        for (int nj = 0; nj < 4; nj++) {
            const int col = wn + nj * 16 + fr;
#pragma unroll
            for (int r2 = 0; r2 < 4; r2++) {
                const int row = wm + mi * 16 + fq * 4 + r2;
                float v = acc[mi][nj][r2] + bias[nj];
                int byte = row * 512 + ((col * 2) ^ ((row & 7) << 4));
                *(unsigned short*)(smem + byte) = f2bf(gelu_fast(v));
            }
        }
    __syncthreads();
    // ---- stream out: 16B/lane fully-coalesced nontemporal (full lines) ----
    char* Cgb = (char*)(G + ((size_t)bs * SEQ + (size_t)mt * 256) * FFN + (size_t)nt * 256);
#pragma unroll
    for (int it = 0; it < 16; it++) {
        int chunk = tid + it * 512;       // 0..8191
        int row = chunk >> 5;
        int cb  = (chunk & 31) * 16;
        s16x8 v = *(const s16x8*)(smem + row * 512 + (cb ^ ((row & 7) << 4)));
        __builtin_nontemporal_store(v, (s16x8*)(Cgb + (size_t)row * (FFN * 2) + cb));
    }
}

// ---------------------------------------------------------------------------
// Kernel 2: Out = G @ W2[e] + b2[e] -> fp32; LDS-coalesced NT epilogue in 2
// column-halves (fp32 tile 256 KB > 128 KB LDS).
// ---------------------------------------------------------------------------
__global__ __launch_bounds__(512, 2) void moe_gemm2(
    const unsigned short* __restrict__ G,
    const int*   __restrict__ labels,
    const int*   __restrict__ perm,
    const unsigned short* __restrict__ W2T,  // [E][HID][FFN]
    const float* __restrict__ B2,
    float* __restrict__ Out)
{
    extern __shared__ char smem[];
    const int L = blockIdx.x;
    const int xcd = L & 7, s = L >> 3;       // s in [0,24)
    const int bs = perm[xcd * 4 + s / 6];
    const int rr = s % 6;
    const int mt = rr / 3, nt = rr % 3;
    const int e  = labels[bs];

    const char* Ag = (const char*)(G + ((size_t)bs * SEQ + (size_t)mt * 256) * FFN);
    const char* Bg = (const char*)(W2T + (size_t)e * HID * FFN + (size_t)nt * 256 * FFN);

    const int tid = threadIdx.x;
    const int lane = tid & 63, w = tid >> 6;
    const int wm = (w >> 2) * 128, wn = (w & 3) * 64;
    const int fr = lane & 15, fq = lane >> 4;
    const int arow_b = (wm + fr) * 128, brow_b = (wn + fr) * 128;
    const int k0 = (fq * 16) ^ ((fr & 7) << 4);

    f32x4 acc[8][4];
#pragma unroll
    for (int i = 0; i < 8; i++)
#pragma unroll
        for (int j = 0; j < 4; j++) acc[i][j] = (f32x4)0.0f;

    gemm_mainloop<FFN * 2>(Ag, Bg, smem, FFN / 64, tid, arow_b, brow_b, k0, acc);

    const float* b2g = B2 + (size_t)e * HID + (size_t)nt * 256;
    float bias[4];
#pragma unroll
    for (int nj = 0; nj < 4; nj++) bias[nj] = b2g[wn + nj * 16 + fr];
    char* Cgb = (char*)(Out + ((size_t)bs * SEQ + (size_t)mt * 256) * HID + (size_t)nt * 256);

#pragma unroll
    for (int half = 0; half < 2; ++half) {
        if ((wn >> 7) == half) {
#pragma unroll
            for (int mi = 0; mi < 8; mi++)
#pragma unroll
                for (int nj = 0; nj < 4; nj++) {
                    const int lcol = (wn & 127) + nj * 16 + fr;   // 0..127
#pragma unroll
                    for (int r2 = 0; r2 < 4; r2++) {
                        const int row = wm + mi * 16 + fq * 4 + r2;
                        int byte = row * 512 + ((lcol * 4) ^ ((row & 7) << 4));
                        *(float*)(smem + byte) = acc[mi][nj][r2] + bias[nj];
                    }
                }
        }
        __syncthreads();
#pragma unroll
        for (int it = 0; it < 16; it++) {
            int chunk = tid + it * 512;
            int row = chunk >> 5;
            int cb  = (chunk & 31) * 16;
            f32x4 v = *(const f32x4*)(smem + row * 512 + (cb ^ ((row & 7) << 4)));
            __builtin_nontemporal_store(v, (f32x4*)(Cgb + (size_t)row * (HID * 4) + half * 512 + cb));
        }
        if (half == 0) __syncthreads();
    }
}

extern "C" void kernel_launch(void* const* d_in, const int* in_sizes, int n_in,
                              void* d_out, int out_size, void* d_ws, size_t ws_size,
                              hipStream_t stream) {
    const float* X      = (const float*)d_in[0];
    const int*   labels = (const int*)  d_in[1];
    const float* W1     = (const float*)d_in[2];
    const float* B1     = (const float*)d_in[3];
    const float* W2     = (const float*)d_in[4];
    const float* B2     = (const float*)d_in[5];
    float* Out = (float*)d_out;

    char* ws = (char*)d_ws;
    unsigned short* Xb  = (unsigned short*)(ws);               // 25,165,824 B
    unsigned short* W1T = (unsigned short*)(ws + 25165824);    // 37,748,736 B
    unsigned short* W2T = (unsigned short*)(ws + 62914560);    // 37,748,736 B
    unsigned short* G   = (unsigned short*)(ws + 100663296);   // 100,663,296 B
    int*            perm = (int*)(ws + 201326592);             // 128 B

    (void)hipFuncSetAttribute((const void*)moe_gemm1,
        hipFuncAttributeMaxDynamicSharedMemorySize, 131072);
    (void)hipFuncSetAttribute((const void*)moe_gemm2,
        hipFuncAttributeMaxDynamicSharedMemorySize, 131072);

    sort_labels_kernel<<<1, 64, 0, stream>>>(labels, perm);
    cvt_x_xcd<<<256, 256, 0, stream>>>(X, perm, Xb);
    cvt_transpose_kernel<<<dim3(FFN / 64, HID / 64, NEXP), 256, 0, stream>>>(W1, W1T, HID, FFN);
    cvt_transpose_kernel<<<dim3(HID / 64, FFN / 64, NEXP), 256, 0, stream>>>(W2, W2T, FFN, HID);

    moe_gemm1<<<768, dim3(512), 131072, stream>>>(Xb, labels, perm, W1T, B1, G);
    moe_gemm2<<<192, dim3(512), 131072, stream>>>(G, labels, perm, W2T, B2, Out);
}